// Round 2
// baseline (619.475 us; speedup 1.0000x reference)
//
#include <hip/hip_runtime.h>

// DepthwiseRREUp: out[b,c,g, 2i+di, 2j+dj] = x[b,c,g,i,j] * rot90(dw[c], g)[di][dj]
// Pure broadcast upsample, memory-bound (134 MB read + 537 MB write, ideal ~107 us
// at 6.3 TB/s).
//
// Layout constants: B=8, C=256, G=4, H=W=64, K=2.
//   x   : [B, C, G, 64, 64]   fp32
//   dw  : [C, 1, 2, 2]        fp32 (4 floats/channel, contiguous)
//   out : [B, C, G, 128, 128] fp32
//
// V2 structure (vs one-shot-thread V1 @ ~2.8 TB/s effective):
//  - one block per m = [b,c,g] image (grid = 8192): filter load + rot90 hoisted,
//    loop-invariant per thread.
//  - each thread: 8 iterations (rows i0, i0+8, ..., i0+56), ALL 8 x-loads issued
//    before any store -> 8 outstanding loads/lane (vs 1) to cover HBM latency.
//  - nontemporal loads/stores: both streams are touch-once; don't thrash L2.
//  - per-store-instruction coalescing preserved: lanes 0-31 write one full
//    512 B output row, lanes 32-63 the row 2 below it.
//
// (Round 1 resubmit: Round 0 attempt hit an infra failure — "container failed
// twice" — before the kernel ever ran. Bounds and graph-capture rules audited;
// source unchanged.)

typedef float f32x2 __attribute__((ext_vector_type(2)));
typedef float f32x4 __attribute__((ext_vector_type(4)));

__global__ __launch_bounds__(256) void DepthwiseRREUp_kernel(
    const float* __restrict__ x,
    const float* __restrict__ dw,
    float* __restrict__ out) {
    const int m  = blockIdx.x;      // b*1024 + c*4 + g, 0..8191
    const int cg = m & 1023;        // c*4 + g
    const int c  = cg >> 2;
    const int g  = cg & 3;          // block-uniform

    const int tid = threadIdx.x;
    const int j2  = tid & 31;       // input col pair (j = 2*j2)
    const int i0  = tid >> 5;       // starting input row, 0..7

    // Wave-uniform 16B filter load, rotation hoisted out of the loop.
    const f32x4 w = *reinterpret_cast<const f32x4*>(dw + (c << 2));
    // rot90 CCW by g of [[a,b],[c,d]]:
    //   g=0: [[a,b],[c,d]]  g=1: [[b,d],[a,c]]  g=2: [[d,c],[b,a]]  g=3: [[c,a],[d,b]]
    float f00, f01, f10, f11;
    switch (g) {
        case 0:  f00 = w.x; f01 = w.y; f10 = w.z; f11 = w.w; break;
        case 1:  f00 = w.y; f01 = w.w; f10 = w.x; f11 = w.z; break;
        case 2:  f00 = w.w; f01 = w.z; f10 = w.y; f11 = w.x; break;
        default: f00 = w.z; f01 = w.x; f10 = w.w; f11 = w.y; break;
    }

    // Base pointers for this thread. Row stride per iteration: 8 input rows
    // (= 512 floats), 16 output rows (= 2048 floats).
    const float* xp = x + (size_t)m * 4096 + i0 * 64 + (j2 << 1);
    float*       op = out + (size_t)m * 16384 + (i0 << 1) * 128 + (j2 << 2);

    // Issue all 8 independent loads first (8 outstanding 8B loads per lane).
    f32x2 xv[8];
#pragma unroll
    for (int it = 0; it < 8; ++it) {
        xv[it] = __builtin_nontemporal_load(
            reinterpret_cast<const f32x2*>(xp + it * 512));
    }

    // Stores drain in order as loads land. Each store instruction per wave
    // covers two full contiguous 512B output rows.
#pragma unroll
    for (int it = 0; it < 8; ++it) {
        const f32x2 v = xv[it];
        const f32x4 o0 = {v.x * f00, v.x * f01, v.y * f00, v.y * f01};
        const f32x4 o1 = {v.x * f10, v.x * f11, v.y * f10, v.y * f11};
        float* r = op + it * 2048;
        __builtin_nontemporal_store(o0, reinterpret_cast<f32x4*>(r));
        __builtin_nontemporal_store(o1, reinterpret_cast<f32x4*>(r + 128));
    }
}

extern "C" void kernel_launch(void* const* d_in, const int* in_sizes, int n_in,
                              void* d_out, int out_size, void* d_ws, size_t ws_size,
                              hipStream_t stream) {
    const float* x  = (const float*)d_in[0];   // [8,256,4,64,64]
    const float* dw = (const float*)d_in[1];   // [256,1,2,2]
    float* out      = (float*)d_out;           // [8,256,4,128,128]

    const int M = in_sizes[0] / 4096;          // B*C*G = 8192 images
    DepthwiseRREUp_kernel<<<M, 256, 0, stream>>>(x, dw, out);
}

// Round 3
// 617.790 us; speedup vs baseline: 1.0027x; 1.0027x over previous
//
#include <hip/hip_runtime.h>

// DepthwiseRREUp: out[b,c,g, 2i+di, 2j+dj] = x[b,c,g,i,j] * rot90(dw[c], g)[di][dj]
// Pure broadcast upsample, memory-bound (134 MB read + 537 MB write, ideal ~107 us
// at 6.3 TB/s).
//
// Layout constants: B=8, C=256, G=4, H=W=64, K=2.
//   x   : [B, C, G, 64, 64]   fp32
//   dw  : [C, 1, 2, 2]        fp32 (4 floats/channel, contiguous)
//   out : [B, C, G, 128, 128] fp32
//
// V3: A/B-disentangle of V2's regression (V1=593us, V2=619us bench; fills equal
// across sessions -> kernel ~250 vs ~280us). V2 bundled {nontemporal, 8-deep
// batching, grid remap}; NT is the suspect (L2-bypass store-through; the rocclr
// fill proves plain cached stores hit 6.3 TB/s). V3 keeps:
//  - V1's exact per-instruction coalescing (wave store = 2x contiguous 512B rows)
//  - PLAIN cached loads/stores (no nt anywhere)
//  - block-uniform filter decode (dw load + rot90 hoisted, 1x per block)
//  - 4-deep load batching (4 outstanding 8B loads/lane, static reg indexing)
// Two blocks per image: block owns 32 input rows (8 rows x 4 iterations).

typedef float f32x2 __attribute__((ext_vector_type(2)));
typedef float f32x4 __attribute__((ext_vector_type(4)));

__global__ __launch_bounds__(256) void DepthwiseRREUp_kernel(
    const float* __restrict__ x,
    const float* __restrict__ dw,
    float* __restrict__ out) {
    const int bb   = blockIdx.x;    // 0..16383
    const int m    = bb >> 1;       // image index b*1024 + c*4 + g
    const int half = bb & 1;        // 0: input rows 0-31, 1: rows 32-63
    const int cg   = m & 1023;
    const int c    = cg >> 2;
    const int g    = cg & 3;        // block-uniform

    const int tid = threadIdx.x;
    const int j2  = tid & 31;                   // input col pair (j = 2*j2)
    const int i0  = (half << 5) + (tid >> 5);   // starting input row

    // Wave-uniform 16B filter load + rot90, once per block.
    const f32x4 w = *reinterpret_cast<const f32x4*>(dw + (c << 2));
    // rot90 CCW by g of [[a,b],[c,d]]:
    //   g=0: [[a,b],[c,d]]  g=1: [[b,d],[a,c]]  g=2: [[d,c],[b,a]]  g=3: [[c,a],[d,b]]
    float f00, f01, f10, f11;
    switch (g) {
        case 0:  f00 = w.x; f01 = w.y; f10 = w.z; f11 = w.w; break;
        case 1:  f00 = w.y; f01 = w.w; f10 = w.x; f11 = w.z; break;
        case 2:  f00 = w.w; f01 = w.z; f10 = w.y; f11 = w.x; break;
        default: f00 = w.z; f01 = w.x; f10 = w.w; f11 = w.y; break;
    }

    // Per-iteration stride: 8 input rows (512 floats) -> 16 output rows (2048).
    const float* xp = x + (size_t)m * 4096 + i0 * 64 + (j2 << 1);
    float*       op = out + (size_t)m * 16384 + (i0 << 1) * 128 + (j2 << 2);

    // 4 independent cached loads issued before any store (static reg indexing).
    f32x2 xv[4];
#pragma unroll
    for (int it = 0; it < 4; ++it) {
        xv[it] = *reinterpret_cast<const f32x2*>(xp + it * 512);
    }

    // Plain cached stores; each store instruction per wave covers two full
    // contiguous 512B output rows (identical pattern to V1).
#pragma unroll
    for (int it = 0; it < 4; ++it) {
        const f32x2 v = xv[it];
        const f32x4 o0 = {v.x * f00, v.x * f01, v.y * f00, v.y * f01};
        const f32x4 o1 = {v.x * f10, v.x * f11, v.y * f10, v.y * f11};
        float* r = op + it * 2048;
        *reinterpret_cast<f32x4*>(r)       = o0;
        *reinterpret_cast<f32x4*>(r + 128) = o1;
    }
}

extern "C" void kernel_launch(void* const* d_in, const int* in_sizes, int n_in,
                              void* d_out, int out_size, void* d_ws, size_t ws_size,
                              hipStream_t stream) {
    const float* x  = (const float*)d_in[0];   // [8,256,4,64,64]
    const float* dw = (const float*)d_in[1];   // [256,1,2,2]
    float* out      = (float*)d_out;           // [8,256,4,128,128]

    const int M = in_sizes[0] / 4096;          // B*C*G = 8192 images
    DepthwiseRREUp_kernel<<<M * 2, 256, 0, stream>>>(x, dw, out);
}